// Round 1
// baseline (118.263 us; speedup 1.0000x reference)
//
#include <hip/hip_runtime.h>
#include <hip/hip_bf16.h>

typedef __bf16 bf16x8 __attribute__((ext_vector_type(8)));
typedef float f32x4 __attribute__((ext_vector_type(4)));

#define TILE 128
#define DDIM 128
#define LDSK 136   // pad 128 -> 136 bf16 (272 B row stride): <=2-way LDS conflicts (free)
#define MARGIN_F 0.2f

// ---- prep: yy[i] = ||y_i||^2, crow[i] = yy_i - 2*x_i.y_i, and zero d_out ----
__global__ __launch_bounds__(256)
void prep_kernel(const float* __restrict__ x, const float* __restrict__ y,
                 float* __restrict__ yy, float* __restrict__ crow,
                 float* __restrict__ out, int N)
{
    const int t    = threadIdx.x;
    const int lane = t & 63;
    const int row  = blockIdx.x * 4 + (t >> 6);   // one wave per row
    const float2* xr = (const float2*)(x + (size_t)row * DDIM);
    const float2* yr = (const float2*)(y + (size_t)row * DDIM);
    const float2 xv = xr[lane];
    const float2 yv = yr[lane];
    float sy  = yv.x * yv.x + yv.y * yv.y;
    float sxy = xv.x * yv.x + xv.y * yv.y;
    #pragma unroll
    for (int off = 32; off; off >>= 1) {
        sy  += __shfl_xor(sy,  off);
        sxy += __shfl_xor(sxy, off);
    }
    if (lane == 0) {
        yy[row]   = sy;
        crow[row] = sy - 2.0f * sxy;
    }
    if (t == 0 && blockIdx.x == 0) out[0] = 0.0f;  // d_out is poisoned each launch
}

// ---- fused GEMM + epilogue + reduction ----
// S = X * Y^T via bf16 MFMA (whole K=128 staged once in LDS),
// loss = relu(2*S + c_i - yy_j + margin), diag zeroed, mean accumulated atomically.
__global__ __launch_bounds__(256)
void triplet_kernel(const float* __restrict__ x, const float* __restrict__ y,
                    const float* __restrict__ yy, const float* __restrict__ crow,
                    float* __restrict__ out, int N, float inv_n2)
{
    __shared__ __bf16 As[TILE][LDSK];
    __shared__ __bf16 Bs[TILE][LDSK];
    __shared__ float ctile[TILE];
    __shared__ float yytile[TILE];
    __shared__ float wsum[4];

    const int t  = threadIdx.x;
    const int bi = blockIdx.y;   // row tile (x)
    const int bj = blockIdx.x;   // col tile (y)

    // ---- stage: fp32 global -> bf16 LDS (16 B per thread per array per iter) ----
    {
        const int rr = t >> 4;        // 0..15
        const int cc = (t & 15) * 8;  // float column base
        const float* xp = x + (size_t)bi * TILE * DDIM;
        const float* yp = y + (size_t)bj * TILE * DDIM;
        #pragma unroll
        for (int it = 0; it < 8; ++it) {
            const int r = it * 16 + rr;
            const float4 a0 = *(const float4*)(xp + (size_t)r * DDIM + cc);
            const float4 a1 = *(const float4*)(xp + (size_t)r * DDIM + cc + 4);
            bf16x8 av;
            av[0] = (__bf16)a0.x; av[1] = (__bf16)a0.y; av[2] = (__bf16)a0.z; av[3] = (__bf16)a0.w;
            av[4] = (__bf16)a1.x; av[5] = (__bf16)a1.y; av[6] = (__bf16)a1.z; av[7] = (__bf16)a1.w;
            *(bf16x8*)&As[r][cc] = av;
            const float4 b0 = *(const float4*)(yp + (size_t)r * DDIM + cc);
            const float4 b1 = *(const float4*)(yp + (size_t)r * DDIM + cc + 4);
            bf16x8 bv;
            bv[0] = (__bf16)b0.x; bv[1] = (__bf16)b0.y; bv[2] = (__bf16)b0.z; bv[3] = (__bf16)b0.w;
            bv[4] = (__bf16)b1.x; bv[5] = (__bf16)b1.y; bv[6] = (__bf16)b1.z; bv[7] = (__bf16)b1.w;
            *(bf16x8*)&Bs[r][cc] = bv;
        }
        if (t < TILE) ctile[t]         = crow[bi * TILE + t];
        else          yytile[t - TILE] = yy[bj * TILE + (t - TILE)];
    }
    __syncthreads();

    const int wave = t >> 6;
    const int lane = t & 63;
    const int wm   = wave >> 1;    // 2x2 waves over the 128x128 tile, 64x64 each
    const int wn   = wave & 1;
    const int l4   = lane >> 4;    // 0..3
    const int l15  = lane & 15;    // 0..15

    f32x4 acc[4][4] = {};

    #pragma unroll
    for (int kk = 0; kk < 4; ++kk) {
        const int kb = kk * 32 + l4 * 8;   // A/B frag: row = l15 (+16*frag), k = quad*8 + j
        bf16x8 af[4], bfv[4];
        #pragma unroll
        for (int mi = 0; mi < 4; ++mi)
            af[mi] = *(const bf16x8*)&As[wm * 64 + mi * 16 + l15][kb];
        #pragma unroll
        for (int ni = 0; ni < 4; ++ni)
            bfv[ni] = *(const bf16x8*)&Bs[wn * 64 + ni * 16 + l15][kb];
        #pragma unroll
        for (int mi = 0; mi < 4; ++mi)
            #pragma unroll
            for (int ni = 0; ni < 4; ++ni)
                acc[mi][ni] = __builtin_amdgcn_mfma_f32_16x16x32_bf16(
                    af[mi], bfv[ni], acc[mi][ni], 0, 0, 0);
    }

    // ---- epilogue: C/D map col=lane&15, row=(lane>>4)*4+reg (m89/m91 verified) ----
    float lsum = 0.0f;
    #pragma unroll
    for (int ni = 0; ni < 4; ++ni) {
        const int ct    = wn * 64 + ni * 16 + l15;
        const float yyv = yytile[ct];
        const int gj    = bj * TILE + ct;
        #pragma unroll
        for (int mi = 0; mi < 4; ++mi) {
            #pragma unroll
            for (int r = 0; r < 4; ++r) {
                const int rt = wm * 64 + mi * 16 + l4 * 4 + r;
                float v = 2.0f * acc[mi][ni][r] + ctile[rt] - yyv + MARGIN_F;
                v = fmaxf(v, 0.0f);
                const int gi = bi * TILE + rt;
                if (gi == gj) v = 0.0f;    // zero the diagonal
                lsum += v;
            }
        }
    }
    #pragma unroll
    for (int off = 32; off; off >>= 1) lsum += __shfl_xor(lsum, off);
    if (lane == 0) wsum[wave] = lsum;
    __syncthreads();
    if (t == 0)
        atomicAdd(out, (wsum[0] + wsum[1] + wsum[2] + wsum[3]) * inv_n2);
}

extern "C" void kernel_launch(void* const* d_in, const int* in_sizes, int n_in,
                              void* d_out, int out_size, void* d_ws, size_t ws_size,
                              hipStream_t stream)
{
    const float* x = (const float*)d_in[0];
    const float* y = (const float*)d_in[1];
    float* out = (float*)d_out;
    const int N = in_sizes[0] / DDIM;          // 8192
    float* yy   = (float*)d_ws;                // N floats
    float* crow = yy + N;                      // N floats (64 KB total ws)
    const float inv_n2 = 1.0f / ((float)N * (float)N);

    prep_kernel<<<dim3(N / 4), dim3(256), 0, stream>>>(x, y, yy, crow, out, N);
    triplet_kernel<<<dim3(N / TILE, N / TILE), dim3(256), 0, stream>>>(
        x, y, yy, crow, out, N, inv_n2);
}

// Round 2
// 94.248 us; speedup vs baseline: 1.2548x; 1.2548x over previous
//
#include <hip/hip_runtime.h>
#include <hip/hip_bf16.h>

typedef __bf16 bf16x8 __attribute__((ext_vector_type(8)));
typedef __bf16 bf16x2 __attribute__((ext_vector_type(2)));
typedef float f32x4 __attribute__((ext_vector_type(4)));

#define TILE 128
#define DDIM 128
#define MARGIN_F 0.2f
#define JPB 4    // j-tiles swept per block (A staged once per block)

__device__ __forceinline__ void async_cp16(const void* g, void* l) {
    __builtin_amdgcn_global_load_lds(
        (const __attribute__((address_space(1))) unsigned int*)g,
        (__attribute__((address_space(3))) unsigned int*)l, 16, 0, 0);
}

// ============================ fast path (bf16 DMA) ============================

// prep: bf16 copies of x,y into ws; yy[i]; crow[i] = yy_i - 2*x_i.y_i + margin; zero out
__global__ __launch_bounds__(256)
void prep_bf16_kernel(const float* __restrict__ x, const float* __restrict__ y,
                      __bf16* __restrict__ xb, __bf16* __restrict__ yb,
                      float* __restrict__ yy, float* __restrict__ crow,
                      float* __restrict__ out)
{
    const int t    = threadIdx.x;
    const int lane = t & 63;
    const int row  = blockIdx.x * 4 + (t >> 6);   // one wave per row
    const float2 xv = ((const float2*)(x + (size_t)row * DDIM))[lane];
    const float2 yv = ((const float2*)(y + (size_t)row * DDIM))[lane];
    bf16x2 xbv; xbv[0] = (__bf16)xv.x; xbv[1] = (__bf16)xv.y;
    bf16x2 ybv; ybv[0] = (__bf16)yv.x; ybv[1] = (__bf16)yv.y;
    *(bf16x2*)(xb + (size_t)row * DDIM + 2 * lane) = xbv;
    *(bf16x2*)(yb + (size_t)row * DDIM + 2 * lane) = ybv;
    float sy  = yv.x * yv.x + yv.y * yv.y;
    float sxy = xv.x * yv.x + xv.y * yv.y;
    #pragma unroll
    for (int off = 32; off; off >>= 1) {
        sy  += __shfl_xor(sy,  off);
        sxy += __shfl_xor(sxy, off);
    }
    if (lane == 0) {
        yy[row]   = sy;
        crow[row] = sy - 2.0f * sxy + MARGIN_F;
    }
    if (t == 0 && blockIdx.x == 0) out[0] = 0.0f;
}

// fused GEMM + epilogue + reduction, bf16 inputs staged via global_load_lds
__global__ __launch_bounds__(256)
void triplet_bf16_kernel(const __bf16* __restrict__ xb, const __bf16* __restrict__ yb,
                         const float* __restrict__ yy, const float* __restrict__ crow,
                         float* __restrict__ out, float inv_n2)
{
    __shared__ __align__(1024) __bf16 As[TILE * DDIM];   // 32 KB, XOR-swizzled chunks
    __shared__ __align__(1024) __bf16 Bs[TILE * DDIM];   // 32 KB
    __shared__ float ctile[TILE];
    __shared__ float yytile[JPB][TILE];
    __shared__ float wsum[4];

    const int t    = threadIdx.x;
    const int w    = t >> 6;
    const int lane = t & 63;
    const int bi   = blockIdx.y;
    const int jg   = blockIdx.x;

    const int lrow = lane >> 4;   // 0..3
    const int lcol = lane & 15;   // chunk column

    // ---- stage A (once) and B(j0) via async DMA; LDS chunk (row,c) = G(row, c^(row&15)) ----
    {
        const __bf16* ga = xb + (size_t)(bi * TILE) * DDIM;
        const __bf16* gb = yb + (size_t)(jg * JPB * TILE) * DDIM;
        char* la = (char*)As + w * 8192;
        char* lb = (char*)Bs + w * 8192;
        #pragma unroll
        for (int s = 0; s < 8; ++s) {
            const int row = w * 32 + s * 4 + lrow;
            const int sc  = lcol ^ (row & 15);
            async_cp16(ga + (size_t)row * DDIM + sc * 8, la + s * 1024);
            async_cp16(gb + (size_t)row * DDIM + sc * 8, lb + s * 1024);
        }
    }
    if (t < TILE) ctile[t] = crow[bi * TILE + t];
    #pragma unroll
    for (int q = 0; q < 2; ++q) {
        const int idx = q * 256 + t;                 // 0..511
        yytile[idx >> 7][idx & 127] = yy[jg * JPB * TILE + idx];
    }
    __syncthreads();   // A + B0 DMA complete, ctile/yytile visible

    const int wm  = w >> 1;     // 2x2 waves, 64x64 each
    const int wn  = w & 1;
    const int l4  = lane >> 4;
    const int l15 = lane & 15;

    // ---- hoist A fragments into registers (read once per block) ----
    bf16x8 af[4][4];
    #pragma unroll
    for (int kk = 0; kk < 4; ++kk) {
        const int colb = (((kk * 4 + l4) ^ l15) << 4);   // swizzled chunk byte offset
        #pragma unroll
        for (int mi = 0; mi < 4; ++mi) {
            const int r = wm * 64 + mi * 16 + l15;
            af[kk][mi] = *(const bf16x8*)((const char*)As + r * 256 + colb);
        }
    }
    float ctv[16];
    #pragma unroll
    for (int mi = 0; mi < 4; ++mi)
        #pragma unroll
        for (int rr = 0; rr < 4; ++rr)
            ctv[mi * 4 + rr] = ctile[wm * 64 + mi * 16 + l4 * 4 + rr];

    float lsum = 0.0f;

    #pragma unroll
    for (int jj = 0; jj < JPB; ++jj) {
        if (jj > 0) __syncthreads();   // B(jj) DMA complete

        f32x4 acc[4][4] = {};
        #pragma unroll
        for (int kk = 0; kk < 4; ++kk) {
            const int colb = (((kk * 4 + l4) ^ l15) << 4);
            bf16x8 bfv[4];
            #pragma unroll
            for (int ni = 0; ni < 4; ++ni)
                bfv[ni] = *(const bf16x8*)((const char*)Bs + (wn * 64 + ni * 16 + l15) * 256 + colb);
            #pragma unroll
            for (int mi = 0; mi < 4; ++mi)
                #pragma unroll
                for (int ni = 0; ni < 4; ++ni)
                    acc[mi][ni] = __builtin_amdgcn_mfma_f32_16x16x32_bf16(
                        af[kk][mi], bfv[ni], acc[mi][ni], 0, 0, 0);
        }
        __syncthreads();               // all waves done reading Bs

        if (jj + 1 < JPB) {            // async prefetch next B-tile; overlaps epilogue
            const int bjn = jg * JPB + jj + 1;
            const __bf16* gb = yb + (size_t)(bjn * TILE) * DDIM;
            char* lb = (char*)Bs + w * 8192;
            #pragma unroll
            for (int s = 0; s < 8; ++s) {
                const int row = w * 32 + s * 4 + lrow;
                const int sc  = lcol ^ (row & 15);
                async_cp16(gb + (size_t)row * DDIM + sc * 8, lb + s * 1024);
            }
        }

        // ---- epilogue: C/D map col=lane&15, row=(lane>>4)*4+reg ----
        const int bj = jg * JPB + jj;
        if (bj != bi) {
            #pragma unroll
            for (int ni = 0; ni < 4; ++ni) {
                const float yyv = yytile[jj][wn * 64 + ni * 16 + l15];
                #pragma unroll
                for (int mi = 0; mi < 4; ++mi)
                    #pragma unroll
                    for (int r = 0; r < 4; ++r)
                        lsum += fmaxf(fmaf(2.0f, acc[mi][ni][r], ctv[mi * 4 + r] - yyv), 0.0f);
            }
        } else {
            #pragma unroll
            for (int ni = 0; ni < 4; ++ni) {
                const int ct    = wn * 64 + ni * 16 + l15;
                const float yyv = yytile[jj][ct];
                #pragma unroll
                for (int mi = 0; mi < 4; ++mi)
                    #pragma unroll
                    for (int r = 0; r < 4; ++r) {
                        const int rt = wm * 64 + mi * 16 + l4 * 4 + r;
                        float v = fmaxf(fmaf(2.0f, acc[mi][ni][r], ctv[mi * 4 + r] - yyv), 0.0f);
                        if (rt == ct) v = 0.0f;   // diagonal
                        lsum += v;
                    }
            }
        }
    }

    #pragma unroll
    for (int off = 32; off; off >>= 1) lsum += __shfl_xor(lsum, off);
    if (lane == 0) wsum[w] = lsum;
    __syncthreads();
    if (t == 0)
        atomicAdd(out, (wsum[0] + wsum[1] + wsum[2] + wsum[3]) * inv_n2);
}

// ====================== fallback path (round-1, fp32 staging) ======================

#define LDSK 136

__global__ __launch_bounds__(256)
void prep_f32_kernel(const float* __restrict__ x, const float* __restrict__ y,
                     float* __restrict__ yy, float* __restrict__ crow,
                     float* __restrict__ out)
{
    const int t    = threadIdx.x;
    const int lane = t & 63;
    const int row  = blockIdx.x * 4 + (t >> 6);
    const float2 xv = ((const float2*)(x + (size_t)row * DDIM))[lane];
    const float2 yv = ((const float2*)(y + (size_t)row * DDIM))[lane];
    float sy  = yv.x * yv.x + yv.y * yv.y;
    float sxy = xv.x * yv.x + xv.y * yv.y;
    #pragma unroll
    for (int off = 32; off; off >>= 1) {
        sy  += __shfl_xor(sy,  off);
        sxy += __shfl_xor(sxy, off);
    }
    if (lane == 0) { yy[row] = sy; crow[row] = sy - 2.0f * sxy; }
    if (t == 0 && blockIdx.x == 0) out[0] = 0.0f;
}

__global__ __launch_bounds__(256)
void triplet_f32_kernel(const float* __restrict__ x, const float* __restrict__ y,
                        const float* __restrict__ yy, const float* __restrict__ crow,
                        float* __restrict__ out, float inv_n2)
{
    __shared__ __bf16 As[TILE][LDSK];
    __shared__ __bf16 Bs[TILE][LDSK];
    __shared__ float ctile[TILE];
    __shared__ float yytile[TILE];
    __shared__ float wsum[4];

    const int t  = threadIdx.x;
    const int bi = blockIdx.y;
    const int bj = blockIdx.x;
    {
        const int rr = t >> 4;
        const int cc = (t & 15) * 8;
        const float* xp = x + (size_t)bi * TILE * DDIM;
        const float* yp = y + (size_t)bj * TILE * DDIM;
        #pragma unroll
        for (int it = 0; it < 8; ++it) {
            const int r = it * 16 + rr;
            const float4 a0 = *(const float4*)(xp + (size_t)r * DDIM + cc);
            const float4 a1 = *(const float4*)(xp + (size_t)r * DDIM + cc + 4);
            bf16x8 av;
            av[0] = (__bf16)a0.x; av[1] = (__bf16)a0.y; av[2] = (__bf16)a0.z; av[3] = (__bf16)a0.w;
            av[4] = (__bf16)a1.x; av[5] = (__bf16)a1.y; av[6] = (__bf16)a1.z; av[7] = (__bf16)a1.w;
            *(bf16x8*)&As[r][cc] = av;
            const float4 b0 = *(const float4*)(yp + (size_t)r * DDIM + cc);
            const float4 b1 = *(const float4*)(yp + (size_t)r * DDIM + cc + 4);
            bf16x8 bv;
            bv[0] = (__bf16)b0.x; bv[1] = (__bf16)b0.y; bv[2] = (__bf16)b0.z; bv[3] = (__bf16)b0.w;
            bv[4] = (__bf16)b1.x; bv[5] = (__bf16)b1.y; bv[6] = (__bf16)b1.z; bv[7] = (__bf16)b1.w;
            *(bf16x8*)&Bs[r][cc] = bv;
        }
        if (t < TILE) ctile[t]         = crow[bi * TILE + t];
        else          yytile[t - TILE] = yy[bj * TILE + (t - TILE)];
    }
    __syncthreads();

    const int wave = t >> 6;
    const int lane = t & 63;
    const int wm   = wave >> 1;
    const int wn   = wave & 1;
    const int l4   = lane >> 4;
    const int l15  = lane & 15;

    f32x4 acc[4][4] = {};
    #pragma unroll
    for (int kk = 0; kk < 4; ++kk) {
        const int kb = kk * 32 + l4 * 8;
        bf16x8 af[4], bfv[4];
        #pragma unroll
        for (int mi = 0; mi < 4; ++mi) af[mi] = *(const bf16x8*)&As[wm * 64 + mi * 16 + l15][kb];
        #pragma unroll
        for (int ni = 0; ni < 4; ++ni) bfv[ni] = *(const bf16x8*)&Bs[wn * 64 + ni * 16 + l15][kb];
        #pragma unroll
        for (int mi = 0; mi < 4; ++mi)
            #pragma unroll
            for (int ni = 0; ni < 4; ++ni)
                acc[mi][ni] = __builtin_amdgcn_mfma_f32_16x16x32_bf16(af[mi], bfv[ni], acc[mi][ni], 0, 0, 0);
    }

    float lsum = 0.0f;
    #pragma unroll
    for (int ni = 0; ni < 4; ++ni) {
        const int ct    = wn * 64 + ni * 16 + l15;
        const float yyv = yytile[ct];
        const int gj    = bj * TILE + ct;
        #pragma unroll
        for (int mi = 0; mi < 4; ++mi)
            #pragma unroll
            for (int r = 0; r < 4; ++r) {
                const int rt = wm * 64 + mi * 16 + l4 * 4 + r;
                float v = fmaxf(2.0f * acc[mi][ni][r] + ctile[rt] - yyv + MARGIN_F, 0.0f);
                if (bi * TILE + rt == gj) v = 0.0f;
                lsum += v;
            }
    }
    #pragma unroll
    for (int off = 32; off; off >>= 1) lsum += __shfl_xor(lsum, off);
    if (lane == 0) wsum[wave] = lsum;
    __syncthreads();
    if (t == 0) atomicAdd(out, (wsum[0] + wsum[1] + wsum[2] + wsum[3]) * inv_n2);
}

// ================================ launch ================================

extern "C" void kernel_launch(void* const* d_in, const int* in_sizes, int n_in,
                              void* d_out, int out_size, void* d_ws, size_t ws_size,
                              hipStream_t stream)
{
    const float* x = (const float*)d_in[0];
    const float* y = (const float*)d_in[1];
    float* out = (float*)d_out;
    const int N = in_sizes[0] / DDIM;          // 8192
    const float inv_n2 = 1.0f / ((float)N * (float)N);

    const size_t bf_bytes = (size_t)N * DDIM * sizeof(__bf16);    // 2 MB each
    const size_t need = 2 * bf_bytes + 2 * (size_t)N * sizeof(float);

    if (ws_size >= need) {
        __bf16* xb  = (__bf16*)d_ws;
        __bf16* yb  = xb + (size_t)N * DDIM;
        float*  yy  = (float*)(yb + (size_t)N * DDIM);
        float*  crw = yy + N;
        prep_bf16_kernel<<<dim3(N / 4), dim3(256), 0, stream>>>(x, y, xb, yb, yy, crw, out);
        triplet_bf16_kernel<<<dim3(N / (TILE * JPB), N / TILE), dim3(256), 0, stream>>>(
            xb, yb, yy, crw, out, inv_n2);
    } else {
        float* yy  = (float*)d_ws;
        float* crw = yy + N;
        prep_f32_kernel<<<dim3(N / 4), dim3(256), 0, stream>>>(x, y, yy, crw, out);
        triplet_f32_kernel<<<dim3(N / TILE, N / TILE), dim3(256), 0, stream>>>(
            x, y, yy, crw, out, inv_n2);
    }
}

// Round 3
// 86.203 us; speedup vs baseline: 1.3719x; 1.0933x over previous
//
#include <hip/hip_runtime.h>
#include <hip/hip_bf16.h>

typedef __bf16 bf16x8 __attribute__((ext_vector_type(8)));
typedef __bf16 bf16x2 __attribute__((ext_vector_type(2)));
typedef float f32x4 __attribute__((ext_vector_type(4)));

#define DDIM 128
#define TM 256          // rows of X per block
#define HN 64           // B half-tile rows (cols of C) per pipeline step
#define JCOLS 1024      // cols swept per block
#define NSTEP (JCOLS / HN)   // 16 pipeline steps
#define MARGIN_F 0.2f

__device__ __forceinline__ void async_cp16(const void* g, void* l) {
    __builtin_amdgcn_global_load_lds(
        (const __attribute__((address_space(1))) unsigned int*)g,
        (__attribute__((address_space(3))) unsigned int*)l, 16, 0, 0);
}

// ============================ fast path ============================

// prep: bf16 copies of x,y; yy[i]; crow[i] = yy_i - 2*x_i.y_i + margin; zero out
__global__ __launch_bounds__(256)
void prep_bf16_kernel(const float* __restrict__ x, const float* __restrict__ y,
                      __bf16* __restrict__ xb, __bf16* __restrict__ yb,
                      float* __restrict__ yy, float* __restrict__ crow,
                      float* __restrict__ out)
{
    const int t    = threadIdx.x;
    const int lane = t & 63;
    const int row  = blockIdx.x * 4 + (t >> 6);
    const float2 xv = ((const float2*)(x + (size_t)row * DDIM))[lane];
    const float2 yv = ((const float2*)(y + (size_t)row * DDIM))[lane];
    bf16x2 xbv; xbv[0] = (__bf16)xv.x; xbv[1] = (__bf16)xv.y;
    bf16x2 ybv; ybv[0] = (__bf16)yv.x; ybv[1] = (__bf16)yv.y;
    *(bf16x2*)(xb + (size_t)row * DDIM + 2 * lane) = xbv;
    *(bf16x2*)(yb + (size_t)row * DDIM + 2 * lane) = ybv;
    float sy  = yv.x * yv.x + yv.y * yv.y;
    float sxy = xv.x * yv.x + xv.y * yv.y;
    #pragma unroll
    for (int off = 32; off; off >>= 1) {
        sy  += __shfl_xor(sy,  off);
        sxy += __shfl_xor(sxy, off);
    }
    if (lane == 0) {
        yy[row]   = sy;
        crow[row] = sy - 2.0f * sxy + MARGIN_F;
    }
    if (t == 0 && blockIdx.x == 0) out[0] = 0.0f;
}

// fused GEMM + epilogue + reduction. 1 block/CU, 8 waves (4x2), A stationary,
// B streamed as 64-row half-tiles through a 3-buffer LDS ring (2-step DMA lead).
__global__ __launch_bounds__(512, 2)
void triplet_bf16_kernel(const __bf16* __restrict__ xb, const __bf16* __restrict__ yb,
                         const float* __restrict__ yy, const float* __restrict__ crow,
                         float* __restrict__ out, float inv_n2)
{
    __shared__ __align__(1024) __bf16 As[TM * DDIM];        // 64 KB, XOR-swizzled 16B chunks
    __shared__ __align__(1024) __bf16 Bs[3][HN * DDIM];     // 3 x 16 KB ring
    __shared__ float ctile[TM];
    __shared__ float yyg[JCOLS];
    __shared__ float wsum[8];

    const int t    = threadIdx.x;
    const int w    = t >> 6;          // 0..7
    const int lane = t & 63;
    const int lrow = lane >> 4;       // 0..3
    const int lcol = lane & 15;
    const int istrip = blockIdx.y;    // 256-row strip of X
    const int jg     = blockIdx.x;    // 1024-col group of Y

    // ---- prologue: DMA A (64 KB) + B steps 0,1; stage ctile/yyg ----
    {
        const __bf16* ga = xb + (size_t)(istrip * TM) * DDIM;
        char* la = (char*)As + w * 8192;
        #pragma unroll
        for (int s = 0; s < 8; ++s) {
            const int row = w * 32 + s * 4 + lrow;
            const int sc  = lcol ^ (row & 15);
            async_cp16(ga + (size_t)row * DDIM + sc * 8, la + s * 1024);
        }
        const __bf16* gb = yb + (size_t)(jg * JCOLS) * DDIM;
        #pragma unroll
        for (int p = 0; p < 2; ++p) {
            char* lb = (char*)Bs[p] + w * 2048;
            #pragma unroll
            for (int s = 0; s < 2; ++s) {
                const int row = w * 8 + s * 4 + lrow;          // 0..63 within half-tile
                const int sc  = lcol ^ (row & 15);
                async_cp16(gb + (size_t)(p * HN + row) * DDIM + sc * 8, lb + s * 1024);
            }
        }
    }
    if (t < TM) ctile[t] = crow[istrip * TM + t];
    yyg[t]       = yy[jg * JCOLS + t];
    yyg[t + 512] = yy[jg * JCOLS + t + 512];
    __syncthreads();   // A, B0, B1 published; ctile/yyg visible

    const int wm  = w >> 1;           // 0..3 : 64-row slice
    const int wn  = w & 1;            // 0..1 : 32-col slice within half-tile
    const int l4  = lane >> 4;
    const int l15 = lane & 15;

    // ---- hoist A fragments (read once) ----
    bf16x8 af[4][4];                  // [kk][mi]
    #pragma unroll
    for (int kk = 0; kk < 4; ++kk) {
        const int colb = (((kk * 4 + l4) ^ l15) << 4);
        #pragma unroll
        for (int mi = 0; mi < 4; ++mi)
            af[kk][mi] = *(const bf16x8*)((const char*)As + (wm * 64 + mi * 16 + l15) * 256 + colb);
    }
    float ctv[16];
    #pragma unroll
    for (int mi = 0; mi < 4; ++mi)
        #pragma unroll
        for (int r = 0; r < 4; ++r)
            ctv[mi * 4 + r] = ctile[wm * 64 + mi * 16 + l4 * 4 + r];

    float lsum = 0.0f;
    const __bf16* gb = yb + (size_t)(jg * JCOLS) * DDIM;

    #pragma unroll
    for (int js = 0; js < NSTEP; ++js) {
        const int b = js % 3;

        // issue DMA for step js+2 into the free ring slot (drained at THIS step's barrier,
        // with the whole compute+epilogue as lead time)
        if (js + 2 < NSTEP) {
            char* lb = (char*)Bs[(js + 2) % 3] + w * 2048;
            #pragma unroll
            for (int s = 0; s < 2; ++s) {
                const int row = w * 8 + s * 4 + lrow;
                const int sc  = lcol ^ (row & 15);
                async_cp16(gb + (size_t)((js + 2) * HN + row) * DDIM + sc * 8, lb + s * 1024);
            }
        }

        // ---- compute 256x64 on ring slot b ----
        f32x4 acc[4][2] = {};
        #pragma unroll
        for (int kk = 0; kk < 4; ++kk) {
            const int colb = (((kk * 4 + l4) ^ l15) << 4);
            bf16x8 bfv[2];
            #pragma unroll
            for (int ni = 0; ni < 2; ++ni)
                bfv[ni] = *(const bf16x8*)((const char*)Bs[b] + (wn * 32 + ni * 16 + l15) * 256 + colb);
            #pragma unroll
            for (int mi = 0; mi < 4; ++mi)
                #pragma unroll
                for (int ni = 0; ni < 2; ++ni)
                    acc[mi][ni] = __builtin_amdgcn_mfma_f32_16x16x32_bf16(
                        af[kk][mi], bfv[ni], acc[mi][ni], 0, 0, 0);
        }

        // ---- epilogue: C/D map col=lane&15, row=(lane>>4)*4+reg ----
        const int g64  = jg * NSTEP + js;          // global 64-col block index
        const bool diag = (g64 >> 2) == istrip;    // this 64-block lies inside our row strip
        const int doff  = (g64 & 3) * 64;
        #pragma unroll
        for (int ni = 0; ni < 2; ++ni) {
            const int cl    = wn * 32 + ni * 16 + l15;
            const float yyv = yyg[js * HN + cl];
            #pragma unroll
            for (int mi = 0; mi < 4; ++mi)
                #pragma unroll
                for (int r = 0; r < 4; ++r) {
                    float v = fmaxf(fmaf(2.0f, acc[mi][ni][r], ctv[mi * 4 + r] - yyv), 0.0f);
                    if (diag) {
                        const int rl = wm * 64 + mi * 16 + l4 * 4 + r;
                        if (rl == doff + cl) v = 0.0f;
                    }
                    lsum += v;
                }
        }

        __syncthreads();   // publishes DMA(js+2); all waves done reading slot for js-? reuse
    }

    #pragma unroll
    for (int off = 32; off; off >>= 1) lsum += __shfl_xor(lsum, off);
    if (lane == 0) wsum[w] = lsum;
    __syncthreads();
    if (t == 0) {
        float s = 0.0f;
        #pragma unroll
        for (int i = 0; i < 8; ++i) s += wsum[i];
        atomicAdd(out, s * inv_n2);
    }
}

// ====================== fallback path (round-1, fp32 staging) ======================

#define TILE 128
#define LDSK 136

__global__ __launch_bounds__(256)
void prep_f32_kernel(const float* __restrict__ x, const float* __restrict__ y,
                     float* __restrict__ yy, float* __restrict__ crow,
                     float* __restrict__ out)
{
    const int t    = threadIdx.x;
    const int lane = t & 63;
    const int row  = blockIdx.x * 4 + (t >> 6);
    const float2 xv = ((const float2*)(x + (size_t)row * DDIM))[lane];
    const float2 yv = ((const float2*)(y + (size_t)row * DDIM))[lane];
    float sy  = yv.x * yv.x + yv.y * yv.y;
    float sxy = xv.x * yv.x + xv.y * yv.y;
    #pragma unroll
    for (int off = 32; off; off >>= 1) {
        sy  += __shfl_xor(sy,  off);
        sxy += __shfl_xor(sxy, off);
    }
    if (lane == 0) { yy[row] = sy; crow[row] = sy - 2.0f * sxy; }
    if (t == 0 && blockIdx.x == 0) out[0] = 0.0f;
}

__global__ __launch_bounds__(256)
void triplet_f32_kernel(const float* __restrict__ x, const float* __restrict__ y,
                        const float* __restrict__ yy, const float* __restrict__ crow,
                        float* __restrict__ out, float inv_n2)
{
    __shared__ __bf16 As[TILE][LDSK];
    __shared__ __bf16 Bs[TILE][LDSK];
    __shared__ float ctile[TILE];
    __shared__ float yytile[TILE];
    __shared__ float wsum[4];

    const int t  = threadIdx.x;
    const int bi = blockIdx.y;
    const int bj = blockIdx.x;
    {
        const int rr = t >> 4;
        const int cc = (t & 15) * 8;
        const float* xp = x + (size_t)bi * TILE * DDIM;
        const float* yp = y + (size_t)bj * TILE * DDIM;
        #pragma unroll
        for (int it = 0; it < 8; ++it) {
            const int r = it * 16 + rr;
            const float4 a0 = *(const float4*)(xp + (size_t)r * DDIM + cc);
            const float4 a1 = *(const float4*)(xp + (size_t)r * DDIM + cc + 4);
            bf16x8 av;
            av[0] = (__bf16)a0.x; av[1] = (__bf16)a0.y; av[2] = (__bf16)a0.z; av[3] = (__bf16)a0.w;
            av[4] = (__bf16)a1.x; av[5] = (__bf16)a1.y; av[6] = (__bf16)a1.z; av[7] = (__bf16)a1.w;
            *(bf16x8*)&As[r][cc] = av;
            const float4 b0 = *(const float4*)(yp + (size_t)r * DDIM + cc);
            const float4 b1 = *(const float4*)(yp + (size_t)r * DDIM + cc + 4);
            bf16x8 bv;
            bv[0] = (__bf16)b0.x; bv[1] = (__bf16)b0.y; bv[2] = (__bf16)b0.z; bv[3] = (__bf16)b0.w;
            bv[4] = (__bf16)b1.x; bv[5] = (__bf16)b1.y; bv[6] = (__bf16)b1.z; bv[7] = (__bf16)b1.w;
            *(bf16x8*)&Bs[r][cc] = bv;
        }
        if (t < TILE) ctile[t]         = crow[bi * TILE + t];
        else          yytile[t - TILE] = yy[bj * TILE + (t - TILE)];
    }
    __syncthreads();

    const int wave = t >> 6;
    const int lane = t & 63;
    const int wm   = wave >> 1;
    const int wn   = wave & 1;
    const int l4   = lane >> 4;
    const int l15  = lane & 15;

    f32x4 acc[4][4] = {};
    #pragma unroll
    for (int kk = 0; kk < 4; ++kk) {
        const int kb = kk * 32 + l4 * 8;
        bf16x8 af[4], bfv[4];
        #pragma unroll
        for (int mi = 0; mi < 4; ++mi) af[mi] = *(const bf16x8*)&As[wm * 64 + mi * 16 + l15][kb];
        #pragma unroll
        for (int ni = 0; ni < 4; ++ni) bfv[ni] = *(const bf16x8*)&Bs[wn * 64 + ni * 16 + l15][kb];
        #pragma unroll
        for (int mi = 0; mi < 4; ++mi)
            #pragma unroll
            for (int ni = 0; ni < 4; ++ni)
                acc[mi][ni] = __builtin_amdgcn_mfma_f32_16x16x32_bf16(af[mi], bfv[ni], acc[mi][ni], 0, 0, 0);
    }

    float lsum = 0.0f;
    #pragma unroll
    for (int ni = 0; ni < 4; ++ni) {
        const int ct    = wn * 64 + ni * 16 + l15;
        const float yyv = yytile[ct];
        const int gj    = bj * TILE + ct;
        #pragma unroll
        for (int mi = 0; mi < 4; ++mi)
            #pragma unroll
            for (int r = 0; r < 4; ++r) {
                const int rt = wm * 64 + mi * 16 + l4 * 4 + r;
                float v = fmaxf(2.0f * acc[mi][ni][r] + ctile[rt] - yyv + MARGIN_F, 0.0f);
                if (bi * TILE + rt == gj) v = 0.0f;
                lsum += v;
            }
    }
    #pragma unroll
    for (int off = 32; off; off >>= 1) lsum += __shfl_xor(lsum, off);
    if (lane == 0) wsum[wave] = lsum;
    __syncthreads();
    if (t == 0) atomicAdd(out, (wsum[0] + wsum[1] + wsum[2] + wsum[3]) * inv_n2);
}

// ================================ launch ================================

extern "C" void kernel_launch(void* const* d_in, const int* in_sizes, int n_in,
                              void* d_out, int out_size, void* d_ws, size_t ws_size,
                              hipStream_t stream)
{
    const float* x = (const float*)d_in[0];
    const float* y = (const float*)d_in[1];
    float* out = (float*)d_out;
    const int N = in_sizes[0] / DDIM;          // 8192
    const float inv_n2 = 1.0f / ((float)N * (float)N);

    const size_t bf_bytes = (size_t)N * DDIM * sizeof(__bf16);
    const size_t need = 2 * bf_bytes + 2 * (size_t)N * sizeof(float);

    if (ws_size >= need && (N % JCOLS) == 0) {
        __bf16* xb  = (__bf16*)d_ws;
        __bf16* yb  = xb + (size_t)N * DDIM;
        float*  yy  = (float*)(yb + (size_t)N * DDIM);
        float*  crw = yy + N;
        prep_bf16_kernel<<<dim3(N / 4), dim3(256), 0, stream>>>(x, y, xb, yb, yy, crw, out);
        triplet_bf16_kernel<<<dim3(N / JCOLS, N / TM), dim3(512), 0, stream>>>(
            xb, yb, yy, crw, out, inv_n2);
    } else {
        float* yy  = (float*)d_ws;
        float* crw = yy + N;
        prep_f32_kernel<<<dim3(N / 4), dim3(256), 0, stream>>>(x, y, yy, crw, out);
        triplet_f32_kernel<<<dim3(N / TILE, N / TILE), dim3(256), 0, stream>>>(
            x, y, yy, crw, out, inv_n2);
    }
}